// Round 5
// baseline (16029.434 us; speedup 1.0000x reference)
//
#include <hip/hip_runtime.h>

// GNODecoder round 5: round-4 was LDS-ISSUE-bound (~3200 ds_read_b128 per
// 64-edge wave-pass = 5x oversubscription of the per-CU LDS pipe vs VALU).
// Fix: 2 edges per lane -> every weight ds_read_b128 feeds 8 FMAs (2 edges
// x 4), halving LDS-pipe demand and doubling ILP. Query ranges are owned
// per-WAVE (QW=11 -> ~110 edges vs 128-slot capacity, ~82% efficiency);
// sacc (44x129) + weights = 74.7 KB LDS via dynamic-smem opt-in (160 KB/CU
// on gfx950, 2 blocks/CU). Fallback QW=6 (64.3 KB) if opt-in rejected.

#define NWAVES 4  // 256 threads

__device__ __forceinline__ float gelu_f(float x) {
    // jax.nn.gelu default (approximate=True, tanh form)
    float x3 = x * x * x;
    float t  = 0.7978845608028654f * fmaf(0.044715f, x3, x);
    float e  = __expf(2.0f * t);
    float r  = __builtin_amdgcn_rcpf(e + 1.0f);
    return 0.5f * x * (1.0f + (1.0f - 2.0f * r));
}

// ---------- sort machinery (proven) ----------

__global__ void hist_kernel(const int* __restrict__ dst, int* __restrict__ hist, int E) {
    int e = blockIdx.x * blockDim.x + threadIdx.x;
    if (e < E) atomicAdd(&hist[dst[e]], 1);
}

__global__ __launch_bounds__(1024) void scan_kernel(const int* __restrict__ hist,
                                                    int* __restrict__ start, int n) {
    __shared__ int wsum[16];
    __shared__ int woff[16];
    int tid = threadIdx.x;
    int lane = tid & 63, wid = tid >> 6;
    int carry = 0;  // meaningful on tid 0 only
    for (int base = 0; base < n; base += 1024) {
        int i = base + tid;
        int v = (i < n) ? hist[i] : 0;
        int incl = v;
#pragma unroll
        for (int off = 1; off < 64; off <<= 1) {
            int t = __shfl_up(incl, off, 64);
            if (lane >= off) incl += t;
        }
        if (lane == 63) wsum[wid] = incl;
        __syncthreads();
        if (tid == 0) {
            int acc = carry;
#pragma unroll
            for (int w = 0; w < 16; ++w) { woff[w] = acc; acc += wsum[w]; }
            carry = acc;
        }
        __syncthreads();
        if (i < n) start[i] = woff[wid] + incl - v;
        __syncthreads();
    }
    if (threadIdx.x == 0) start[n] = carry;
}

__global__ void scatter_kernel(const int* __restrict__ dst, const int* __restrict__ src,
                               const int* __restrict__ start, int* __restrict__ cursor,
                               int* __restrict__ dsts, int* __restrict__ srcs, int E) {
    int e = blockIdx.x * blockDim.x + threadIdx.x;
    if (e >= E) return;
    int d = dst[e];
    int pos = start[d] + atomicAdd(&cursor[d], 1);
    dsts[pos] = d;
    srcs[pos] = src[e];
}

// ---------- fused: 2-edge-per-lane MLP + wave-owned segmented mean ----------

// LDS float-offset layout (weights first: const ds-offsets stay < 64 KB)
// W0t [64][8]: rows {W0[0..5][j], b0[j], pad}
#define OFF_W0T  0      // 512 floats
#define OFF_B1   512    // 64
#define OFF_W1   576    // 4096  (W1[64][64] row-major)
#define OFF_B2   4672   // 128
#define OFF_W2   4800   // 8192  (W2[64][128] row-major)
#define OFF_SACC 12992  // QB*129

template <int QW, bool FUSED_PROJ>
__global__ __launch_bounds__(256, 2) void fused_kernel(
    const float* __restrict__ rndata,   // [NL,128]
    const float* __restrict__ qpos,     // [NQ,3]
    const float* __restrict__ lpos,     // [NL,3]
    const int*   __restrict__ dsts,     // [E] sorted by dst
    const int*   __restrict__ srcs,     // [E]
    const int*   __restrict__ start,    // [NQ+1]
    const float* __restrict__ W0, const float* __restrict__ b0,
    const float* __restrict__ W1, const float* __restrict__ b1,
    const float* __restrict__ W2, const float* __restrict__ b2,
    const float* __restrict__ P0, const float* __restrict__ pb0,
    const float* __restrict__ P1, const float* __restrict__ pb1,
    float* __restrict__ agg,            // [NQ,128] mean (path A)
    float* __restrict__ out,            // [NQ,4]   (FUSED_PROJ)
    int nq)
{
    constexpr int QB = QW * NWAVES;
    extern __shared__ float smem[];

    // ---- stage weights ----
    if (threadIdx.x < 64) {
        int j = threadIdx.x;
        float* r = smem + OFF_W0T + j * 8;
        r[0] = W0[0 * 64 + j]; r[1] = W0[1 * 64 + j]; r[2] = W0[2 * 64 + j];
        r[3] = W0[3 * 64 + j]; r[4] = W0[4 * 64 + j]; r[5] = W0[5 * 64 + j];
        r[6] = b0[j];          r[7] = 0.f;
        smem[OFF_B1 + j] = b1[j];
    } else if (threadIdx.x < 96) {
        int j = threadIdx.x - 64;
        ((float4*)(smem + OFF_B2))[j] = ((const float4*)b2)[j];
    }
    {
        const float4* g1 = (const float4*)W1; float4* s1 = (float4*)(smem + OFF_W1);
        for (int i = threadIdx.x; i < 1024; i += 256) s1[i] = g1[i];
        const float4* g2 = (const float4*)W2; float4* s2 = (float4*)(smem + OFF_W2);
        for (int i = threadIdx.x; i < 2048; i += 256) s2[i] = g2[i];
    }
    for (int i = threadIdx.x; i < QB * 129; i += 256) smem[OFF_SACC + i] = 0.f;
    __syncthreads();

    int w = threadIdx.x >> 6, lane = threadIdx.x & 63;
    int q0w = blockIdx.x * QB + w * QW;

    if (q0w < nq) {
        int qendw = min(q0w + QW, nq);
        int e0 = start[q0w], e1 = start[qendw];
        float* saccw = smem + OFF_SACC + (w * QW) * 129;

        for (int base = e0; base < e1; base += 128) {
            int  eA = base + lane, eB = base + 64 + lane;
            bool vA = eA < e1,     vB = eB < e1;
            int  dA = vA ? dsts[eA] : q0w;  int sA = vA ? srcs[eA] : 0;
            int  dB = vB ? dsts[eB] : q0w;  int sB = vB ? srcs[eB] : 0;
            const float* p;
            p = qpos + dA * 3; float qA0 = p[0], qA1 = p[1], qA2 = p[2];
            p = lpos + sA * 3; float lA0 = p[0], lA1 = p[1], lA2 = p[2];
            p = qpos + dB * 3; float qB0 = p[0], qB1 = p[1], qB2 = p[2];
            p = lpos + sB * 3; float lB0 = p[0], lB1 = p[1], lB2 = p[2];

            float h1A[64], h1B[64];
#pragma unroll
            for (int c = 0; c < 64; ++c) { h1A[c] = 0.f; h1B[c] = 0.f; }

            // ---- layer0 (chunked) + layer1 accumulate, weights shared A/B ----
#pragma unroll 1
            for (int i = 0; i < 64; ++i) {
                const float4* w0r = (const float4*)(smem + OFF_W0T + i * 8);
                float4 wa = w0r[0], wb = w0r[1];
                float aA = wb.z, aB = wb.z;
                aA = fmaf(qA0, wa.x, aA); aB = fmaf(qB0, wa.x, aB);
                aA = fmaf(qA1, wa.y, aA); aB = fmaf(qB1, wa.y, aB);
                aA = fmaf(qA2, wa.z, aA); aB = fmaf(qB2, wa.z, aB);
                aA = fmaf(lA0, wa.w, aA); aB = fmaf(lB0, wa.w, aB);
                aA = fmaf(lA1, wb.x, aA); aB = fmaf(lB1, wb.x, aB);
                aA = fmaf(lA2, wb.y, aA); aB = fmaf(lB2, wb.y, aB);
                float h0A = gelu_f(aA), h0B = gelu_f(aB);
                const float4* w1r = (const float4*)(smem + OFF_W1 + i * 64);
#pragma unroll
                for (int c4 = 0; c4 < 16; ++c4) {
                    float4 wv = w1r[c4];
                    h1A[4 * c4 + 0] = fmaf(h0A, wv.x, h1A[4 * c4 + 0]);
                    h1B[4 * c4 + 0] = fmaf(h0B, wv.x, h1B[4 * c4 + 0]);
                    h1A[4 * c4 + 1] = fmaf(h0A, wv.y, h1A[4 * c4 + 1]);
                    h1B[4 * c4 + 1] = fmaf(h0B, wv.y, h1B[4 * c4 + 1]);
                    h1A[4 * c4 + 2] = fmaf(h0A, wv.z, h1A[4 * c4 + 2]);
                    h1B[4 * c4 + 2] = fmaf(h0B, wv.z, h1B[4 * c4 + 2]);
                    h1A[4 * c4 + 3] = fmaf(h0A, wv.w, h1A[4 * c4 + 3]);
                    h1B[4 * c4 + 3] = fmaf(h0B, wv.w, h1B[4 * c4 + 3]);
                }
            }
            // bias + gelu
            {
                const float4* b1r = (const float4*)(smem + OFF_B1);
#pragma unroll
                for (int c4 = 0; c4 < 16; ++c4) {
                    float4 bv = b1r[c4];
                    h1A[4 * c4 + 0] = gelu_f(h1A[4 * c4 + 0] + bv.x);
                    h1B[4 * c4 + 0] = gelu_f(h1B[4 * c4 + 0] + bv.x);
                    h1A[4 * c4 + 1] = gelu_f(h1A[4 * c4 + 1] + bv.y);
                    h1B[4 * c4 + 1] = gelu_f(h1B[4 * c4 + 1] + bv.y);
                    h1A[4 * c4 + 2] = gelu_f(h1A[4 * c4 + 2] + bv.z);
                    h1B[4 * c4 + 2] = gelu_f(h1B[4 * c4 + 2] + bv.z);
                    h1A[4 * c4 + 3] = gelu_f(h1A[4 * c4 + 3] + bv.w);
                    h1B[4 * c4 + 3] = gelu_f(h1B[4 * c4 + 3] + bv.w);
                }
            }

            // ---- layer2 (chunked over 16 output groups), weights shared A/B ----
            float* saccA = saccw + (dA - q0w) * 129;
            float* saccB = saccw + (dB - q0w) * 129;
            const float4* rA = (const float4*)(rndata + (size_t)sA * 128);
            const float4* rB = (const float4*)(rndata + (size_t)sB * 128);
#pragma unroll 1
            for (int jj = 0; jj < 16; ++jj) {
                const float4* bb = (const float4*)(smem + OFF_B2 + jj * 8);
                float4 b20 = bb[0], b21 = bb[1];
                float4 rA0 = rA[jj * 2], rA1 = rA[jj * 2 + 1];
                float4 rB0 = rB[jj * 2], rB1 = rB[jj * 2 + 1];
                float accA[8] = {b20.x, b20.y, b20.z, b20.w, b21.x, b21.y, b21.z, b21.w};
                float accB[8] = {b20.x, b20.y, b20.z, b20.w, b21.x, b21.y, b21.z, b21.w};
                const float* w2c = smem + OFF_W2 + jj * 8;
#pragma unroll
                for (int i2 = 0; i2 < 64; ++i2) {
                    const float4* wr = (const float4*)(w2c + i2 * 128);
                    float4 w0v = wr[0], w1v = wr[1];
                    accA[0] = fmaf(h1A[i2], w0v.x, accA[0]);
                    accB[0] = fmaf(h1B[i2], w0v.x, accB[0]);
                    accA[1] = fmaf(h1A[i2], w0v.y, accA[1]);
                    accB[1] = fmaf(h1B[i2], w0v.y, accB[1]);
                    accA[2] = fmaf(h1A[i2], w0v.z, accA[2]);
                    accB[2] = fmaf(h1B[i2], w0v.z, accB[2]);
                    accA[3] = fmaf(h1A[i2], w0v.w, accA[3]);
                    accB[3] = fmaf(h1B[i2], w0v.w, accB[3]);
                    accA[4] = fmaf(h1A[i2], w1v.x, accA[4]);
                    accB[4] = fmaf(h1B[i2], w1v.x, accB[4]);
                    accA[5] = fmaf(h1A[i2], w1v.y, accA[5]);
                    accB[5] = fmaf(h1B[i2], w1v.y, accB[5]);
                    accA[6] = fmaf(h1A[i2], w1v.z, accA[6]);
                    accB[6] = fmaf(h1B[i2], w1v.z, accB[6]);
                    accA[7] = fmaf(h1A[i2], w1v.w, accA[7]);
                    accB[7] = fmaf(h1B[i2], w1v.w, accB[7]);
                }
                if (vA) {
                    atomicAdd(&saccA[jj * 8 + 0], accA[0] * rA0.x);
                    atomicAdd(&saccA[jj * 8 + 1], accA[1] * rA0.y);
                    atomicAdd(&saccA[jj * 8 + 2], accA[2] * rA0.z);
                    atomicAdd(&saccA[jj * 8 + 3], accA[3] * rA0.w);
                    atomicAdd(&saccA[jj * 8 + 4], accA[4] * rA1.x);
                    atomicAdd(&saccA[jj * 8 + 5], accA[5] * rA1.y);
                    atomicAdd(&saccA[jj * 8 + 6], accA[6] * rA1.z);
                    atomicAdd(&saccA[jj * 8 + 7], accA[7] * rA1.w);
                }
                if (vB) {
                    atomicAdd(&saccB[jj * 8 + 0], accB[0] * rB0.x);
                    atomicAdd(&saccB[jj * 8 + 1], accB[1] * rB0.y);
                    atomicAdd(&saccB[jj * 8 + 2], accB[2] * rB0.z);
                    atomicAdd(&saccB[jj * 8 + 3], accB[3] * rB0.w);
                    atomicAdd(&saccB[jj * 8 + 4], accB[4] * rB1.x);
                    atomicAdd(&saccB[jj * 8 + 5], accB[5] * rB1.y);
                    atomicAdd(&saccB[jj * 8 + 6], accB[6] * rB1.z);
                    atomicAdd(&saccB[jj * 8 + 7], accB[7] * rB1.w);
                }
            }
        }
    }
    __syncthreads();  // ds_add -> ds_read ordering (and uniform exit)

    if (!FUSED_PROJ) {
        if (q0w < nq) {
            int qendw = min(q0w + QW, nq);
            for (int idx = lane; idx < QW * 128; idx += 64) {
                int ql = idx >> 7, c = idx & 127;
                int q = q0w + ql;
                if (q < qendw) {
                    float deg = (float)(start[q + 1] - start[q]);
                    agg[(size_t)q * 128 + c] =
                        smem[OFF_SACC + (w * QW + ql) * 129 + c] / fmaxf(deg, 1.f);
                }
            }
        }
    } else {
        if (q0w < nq && lane < QW && (q0w + lane) < nq) {
            int q = q0w + lane;
            float deg = (float)(start[q + 1] - start[q]);
            float inv = 1.0f / fmaxf(deg, 1.f);
            const float* aq = smem + OFF_SACC + (w * QW + lane) * 129;
            float o0 = pb1[0], o1 = pb1[1], o2 = pb1[2], o3 = pb1[3];
#pragma unroll 1
            for (int jj = 0; jj < 256; jj += 8) {
                float acc[8];
#pragma unroll
                for (int u = 0; u < 8; ++u) acc[u] = pb0[jj + u];
#pragma unroll
                for (int i = 0; i < 128; ++i) {
                    float av = aq[i] * inv;
#pragma unroll
                    for (int u = 0; u < 8; ++u)
                        acc[u] = fmaf(av, P0[i * 256 + jj + u], acc[u]);
                }
#pragma unroll
                for (int u = 0; u < 8; ++u) {
                    float h = gelu_f(acc[u]);
                    o0 = fmaf(h, P1[(jj + u) * 4 + 0], o0);
                    o1 = fmaf(h, P1[(jj + u) * 4 + 1], o1);
                    o2 = fmaf(h, P1[(jj + u) * 4 + 2], o2);
                    o3 = fmaf(h, P1[(jj + u) * 4 + 3], o3);
                }
            }
            float4* o4 = (float4*)(out + (size_t)q * 4);
            *o4 = make_float4(o0, o1, o2, o3);
        }
    }
}

// ---------- projection (path A) ----------

__global__ __launch_bounds__(256) void proj_kernel(
    const float* __restrict__ agg,      // [NQ,128] mean
    const float* __restrict__ P0, const float* __restrict__ pb0,
    const float* __restrict__ P1, const float* __restrict__ pb1,
    float* __restrict__ out, int nq)
{
    int q = blockIdx.x * blockDim.x + threadIdx.x;
    if (q >= nq) return;

    float a[128];
    const float4* ag4 = (const float4*)(agg + (size_t)q * 128);
#pragma unroll
    for (int i = 0; i < 32; ++i) {
        float4 v = ag4[i];
        a[4 * i + 0] = v.x; a[4 * i + 1] = v.y;
        a[4 * i + 2] = v.z; a[4 * i + 3] = v.w;
    }

    float o0 = pb1[0], o1 = pb1[1], o2 = pb1[2], o3 = pb1[3];
#pragma unroll 1
    for (int jj = 0; jj < 256; jj += 8) {
        float acc[8];
#pragma unroll
        for (int u = 0; u < 8; ++u) acc[u] = pb0[jj + u];
#pragma unroll
        for (int i = 0; i < 128; ++i) {
            float av = a[i];
#pragma unroll
            for (int u = 0; u < 8; ++u)
                acc[u] = fmaf(av, P0[i * 256 + jj + u], acc[u]);
        }
#pragma unroll
        for (int u = 0; u < 8; ++u) {
            float h = gelu_f(acc[u]);
            o0 = fmaf(h, P1[(jj + u) * 4 + 0], o0);
            o1 = fmaf(h, P1[(jj + u) * 4 + 1], o1);
            o2 = fmaf(h, P1[(jj + u) * 4 + 2], o2);
            o3 = fmaf(h, P1[(jj + u) * 4 + 3], o3);
        }
    }
    float4* o4 = (float4*)(out + (size_t)q * 4);
    *o4 = make_float4(o0, o1, o2, o3);
}

extern "C" void kernel_launch(void* const* d_in, const int* in_sizes, int n_in,
                              void* d_out, int out_size, void* d_ws, size_t ws_size,
                              hipStream_t stream)
{
    const float* rndata = (const float*)d_in[0];
    const float* qpos   = (const float*)d_in[1];
    const float* lpos   = (const float*)d_in[2];
    const int*   dst    = (const int*)d_in[3];
    const int*   src    = (const int*)d_in[4];
    const float* W0  = (const float*)d_in[5];
    const float* b0  = (const float*)d_in[6];
    const float* W1  = (const float*)d_in[7];
    const float* b1  = (const float*)d_in[8];
    const float* W2  = (const float*)d_in[9];
    const float* b2  = (const float*)d_in[10];
    const float* P0  = (const float*)d_in[11];
    const float* pb0 = (const float*)d_in[12];
    const float* P1  = (const float*)d_in[13];
    const float* pb1 = (const float*)d_in[14];

    int nq = in_sizes[1] / 3;
    int E  = in_sizes[3];

    // ws layout: [agg nq*128 (path A)] [hist] [cursor] [start] [dsts] [srcs]
    size_t agg_bytes  = (size_t)nq * 128 * sizeof(float);
    size_t sort_bytes = 0;
    {
        size_t o = 0;
        o += ((size_t)nq * sizeof(int) + 15) & ~(size_t)15;
        o += ((size_t)nq * sizeof(int) + 15) & ~(size_t)15;
        o += ((size_t)(nq + 1) * sizeof(int) + 15) & ~(size_t)15;
        o += ((size_t)E * sizeof(int) + 15) & ~(size_t)15;
        o += ((size_t)E * sizeof(int) + 15) & ~(size_t)15;
        sort_bytes = o;
    }
    bool path_a = (agg_bytes + sort_bytes) <= ws_size;

    size_t off = path_a ? agg_bytes : 0;
    auto alloc = [&](size_t bytes) {
        void* p = (char*)d_ws + off;
        off += (bytes + 15) & ~(size_t)15;
        return p;
    };
    float* agg   = (float*)d_ws;  // path A only
    int* hist    = (int*)alloc((size_t)nq * sizeof(int));
    int* cursor  = (int*)alloc((size_t)nq * sizeof(int));
    int* start   = (int*)alloc((size_t)(nq + 1) * sizeof(int));
    int* dsts    = (int*)alloc((size_t)E * sizeof(int));
    int* srcs    = (int*)alloc((size_t)E * sizeof(int));

    size_t histpad = ((size_t)nq * sizeof(int) + 15) & ~(size_t)15;
    hipMemsetAsync(hist, 0, 2 * histpad, stream);

    hist_kernel<<<(E + 255) / 256, 256, 0, stream>>>(dst, hist, E);
    scan_kernel<<<1, 1024, 0, stream>>>(hist, start, nq);
    scatter_kernel<<<(E + 255) / 256, 256, 0, stream>>>(dst, src, start, cursor, dsts, srcs, E);

    constexpr int    QW_BIG    = 11;
    constexpr int    QW_SMALL  = 6;
    constexpr size_t SMEM_BIG   = (size_t)(12992 + QW_BIG   * NWAVES * 129) * 4;  // 74,672 B
    constexpr size_t SMEM_SMALL = (size_t)(12992 + QW_SMALL * NWAVES * 129) * 4;  // 64,352 B

    if (path_a) {
        bool big = hipFuncSetAttribute(
            reinterpret_cast<const void*>(&fused_kernel<QW_BIG, false>),
            hipFuncAttributeMaxDynamicSharedMemorySize, (int)SMEM_BIG) == hipSuccess;
        if (big) {
            int nb = (nq + QW_BIG * NWAVES - 1) / (QW_BIG * NWAVES);
            fused_kernel<QW_BIG, false><<<nb, 256, SMEM_BIG, stream>>>(
                rndata, qpos, lpos, dsts, srcs, start,
                W0, b0, W1, b1, W2, b2, P0, pb0, P1, pb1, agg, nullptr, nq);
        } else {
            int nb = (nq + QW_SMALL * NWAVES - 1) / (QW_SMALL * NWAVES);
            fused_kernel<QW_SMALL, false><<<nb, 256, SMEM_SMALL, stream>>>(
                rndata, qpos, lpos, dsts, srcs, start,
                W0, b0, W1, b1, W2, b2, P0, pb0, P1, pb1, agg, nullptr, nq);
        }
        proj_kernel<<<(nq + 255) / 256, 256, 0, stream>>>(
            agg, P0, pb0, P1, pb1, (float*)d_out, nq);
    } else {
        bool big = hipFuncSetAttribute(
            reinterpret_cast<const void*>(&fused_kernel<QW_BIG, true>),
            hipFuncAttributeMaxDynamicSharedMemorySize, (int)SMEM_BIG) == hipSuccess;
        if (big) {
            int nb = (nq + QW_BIG * NWAVES - 1) / (QW_BIG * NWAVES);
            fused_kernel<QW_BIG, true><<<nb, 256, SMEM_BIG, stream>>>(
                rndata, qpos, lpos, dsts, srcs, start,
                W0, b0, W1, b1, W2, b2, P0, pb0, P1, pb1, nullptr, (float*)d_out, nq);
        } else {
            int nb = (nq + QW_SMALL * NWAVES - 1) / (QW_SMALL * NWAVES);
            fused_kernel<QW_SMALL, true><<<nb, 256, SMEM_SMALL, stream>>>(
                rndata, qpos, lpos, dsts, srcs, start,
                W0, b0, W1, b1, W2, b2, P0, pb0, P1, pb1, nullptr, (float*)d_out, nq);
        }
    }
}

// Round 6
// 14045.161 us; speedup vs baseline: 1.1413x; 1.1413x over previous
//
#include <hip/hip_runtime.h>

// GNODecoder round 6: round-5's 2-edge-per-lane idea was right but the
// register allocator chose 128 VGPR (needs ~190) and spilled h1A/h1B to
// scratch -> 46 GB HBM traffic. Fixes:
//  (1) amdgpu_waves_per_eu(2,2): pin allocator to a 256-VGPR budget, no spill.
//  (2) block-shared sacc (QB=48 queries/block), 4 waves sweep the block's
//      sorted edge range in 128-edge chunks -> ~94% slot efficiency.
// LDS 76.7 KB/block -> 2 blocks/CU (153/160 KB), 8 waves/CU.

#define NWAVES 4  // 256 threads

__device__ __forceinline__ float gelu_f(float x) {
    // jax.nn.gelu default (approximate=True, tanh form)
    float x3 = x * x * x;
    float t  = 0.7978845608028654f * fmaf(0.044715f, x3, x);
    float e  = __expf(2.0f * t);
    float r  = __builtin_amdgcn_rcpf(e + 1.0f);
    return 0.5f * x * (1.0f + (1.0f - 2.0f * r));
}

// ---------- sort machinery (proven) ----------

__global__ void hist_kernel(const int* __restrict__ dst, int* __restrict__ hist, int E) {
    int e = blockIdx.x * blockDim.x + threadIdx.x;
    if (e < E) atomicAdd(&hist[dst[e]], 1);
}

__global__ __launch_bounds__(1024) void scan_kernel(const int* __restrict__ hist,
                                                    int* __restrict__ start, int n) {
    __shared__ int wsum[16];
    __shared__ int woff[16];
    int tid = threadIdx.x;
    int lane = tid & 63, wid = tid >> 6;
    int carry = 0;  // meaningful on tid 0 only
    for (int base = 0; base < n; base += 1024) {
        int i = base + tid;
        int v = (i < n) ? hist[i] : 0;
        int incl = v;
#pragma unroll
        for (int off = 1; off < 64; off <<= 1) {
            int t = __shfl_up(incl, off, 64);
            if (lane >= off) incl += t;
        }
        if (lane == 63) wsum[wid] = incl;
        __syncthreads();
        if (tid == 0) {
            int acc = carry;
#pragma unroll
            for (int w = 0; w < 16; ++w) { woff[w] = acc; acc += wsum[w]; }
            carry = acc;
        }
        __syncthreads();
        if (i < n) start[i] = woff[wid] + incl - v;
        __syncthreads();
    }
    if (threadIdx.x == 0) start[n] = carry;
}

__global__ void scatter_kernel(const int* __restrict__ dst, const int* __restrict__ src,
                               const int* __restrict__ start, int* __restrict__ cursor,
                               int* __restrict__ dsts, int* __restrict__ srcs, int E) {
    int e = blockIdx.x * blockDim.x + threadIdx.x;
    if (e >= E) return;
    int d = dst[e];
    int pos = start[d] + atomicAdd(&cursor[d], 1);
    dsts[pos] = d;
    srcs[pos] = src[e];
}

// ---------- fused: 2-edge-per-lane MLP + block-shared segmented mean ----------

// LDS float-offset layout (weights first: const ds-offsets stay < 64 KB)
#define OFF_W0T  0      // 512  (64 rows x {W0[0..5][j], b0[j], pad})
#define OFF_B1   512    // 64
#define OFF_W1   576    // 4096 (W1[64][64] row-major)
#define OFF_B2   4672   // 128
#define OFF_W2   4800   // 8192 (W2[64][128] row-major)
#define OFF_SACC 12992  // QB*129

template <int QB, bool FUSED_PROJ>
__global__
__launch_bounds__(256)
__attribute__((amdgpu_waves_per_eu(2, 2)))
void fused_kernel(
    const float* __restrict__ rndata,   // [NL,128]
    const float* __restrict__ qpos,     // [NQ,3]
    const float* __restrict__ lpos,     // [NL,3]
    const int*   __restrict__ dsts,     // [E] sorted by dst
    const int*   __restrict__ srcs,     // [E]
    const int*   __restrict__ start,    // [NQ+1]
    const float* __restrict__ W0, const float* __restrict__ b0,
    const float* __restrict__ W1, const float* __restrict__ b1,
    const float* __restrict__ W2, const float* __restrict__ b2,
    const float* __restrict__ P0, const float* __restrict__ pb0,
    const float* __restrict__ P1, const float* __restrict__ pb1,
    float* __restrict__ agg,            // [NQ,128] mean (path A)
    float* __restrict__ out,            // [NQ,4]   (FUSED_PROJ)
    int nq)
{
    extern __shared__ float smem[];

    // ---- stage weights ----
    if (threadIdx.x < 64) {
        int j = threadIdx.x;
        float* r = smem + OFF_W0T + j * 8;
        r[0] = W0[0 * 64 + j]; r[1] = W0[1 * 64 + j]; r[2] = W0[2 * 64 + j];
        r[3] = W0[3 * 64 + j]; r[4] = W0[4 * 64 + j]; r[5] = W0[5 * 64 + j];
        r[6] = b0[j];          r[7] = 0.f;
        smem[OFF_B1 + j] = b1[j];
    } else if (threadIdx.x < 96) {
        int j = threadIdx.x - 64;
        ((float4*)(smem + OFF_B2))[j] = ((const float4*)b2)[j];
    }
    {
        const float4* g1 = (const float4*)W1; float4* s1 = (float4*)(smem + OFF_W1);
        for (int i = threadIdx.x; i < 1024; i += 256) s1[i] = g1[i];
        const float4* g2 = (const float4*)W2; float4* s2 = (float4*)(smem + OFF_W2);
        for (int i = threadIdx.x; i < 2048; i += 256) s2[i] = g2[i];
    }
    for (int i = threadIdx.x; i < QB * 129; i += 256) smem[OFF_SACC + i] = 0.f;
    __syncthreads();

    int w = threadIdx.x >> 6, lane = threadIdx.x & 63;
    int q0   = blockIdx.x * QB;
    int qend = min(q0 + QB, nq);
    int e0 = start[q0], e1 = start[qend];
    float* sacc = smem + OFF_SACC;

    for (int base = e0 + w * 128; base < e1; base += NWAVES * 128) {
        int  eA = base + lane, eB = base + 64 + lane;
        bool vA = eA < e1,     vB = eB < e1;
        int  dA = vA ? dsts[eA] : q0;  int sA = vA ? srcs[eA] : 0;
        int  dB = vB ? dsts[eB] : q0;  int sB = vB ? srcs[eB] : 0;
        const float* p;
        p = qpos + dA * 3; float qA0 = p[0], qA1 = p[1], qA2 = p[2];
        p = lpos + sA * 3; float lA0 = p[0], lA1 = p[1], lA2 = p[2];
        p = qpos + dB * 3; float qB0 = p[0], qB1 = p[1], qB2 = p[2];
        p = lpos + sB * 3; float lB0 = p[0], lB1 = p[1], lB2 = p[2];

        float h1A[64], h1B[64];
#pragma unroll
        for (int c = 0; c < 64; ++c) { h1A[c] = 0.f; h1B[c] = 0.f; }

        // ---- layer0 (streamed) + layer1 accumulate, weights shared A/B ----
#pragma unroll 1
        for (int i = 0; i < 64; ++i) {
            const float4* w0r = (const float4*)(smem + OFF_W0T + i * 8);
            float4 wa = w0r[0], wb = w0r[1];
            float aA = wb.z, aB = wb.z;
            aA = fmaf(qA0, wa.x, aA); aB = fmaf(qB0, wa.x, aB);
            aA = fmaf(qA1, wa.y, aA); aB = fmaf(qB1, wa.y, aB);
            aA = fmaf(qA2, wa.z, aA); aB = fmaf(qB2, wa.z, aB);
            aA = fmaf(lA0, wa.w, aA); aB = fmaf(lB0, wa.w, aB);
            aA = fmaf(lA1, wb.x, aA); aB = fmaf(lB1, wb.x, aB);
            aA = fmaf(lA2, wb.y, aA); aB = fmaf(lB2, wb.y, aB);
            float h0A = gelu_f(aA), h0B = gelu_f(aB);
            const float4* w1r = (const float4*)(smem + OFF_W1 + i * 64);
#pragma unroll
            for (int c4 = 0; c4 < 16; ++c4) {
                float4 wv = w1r[c4];
                h1A[4 * c4 + 0] = fmaf(h0A, wv.x, h1A[4 * c4 + 0]);
                h1B[4 * c4 + 0] = fmaf(h0B, wv.x, h1B[4 * c4 + 0]);
                h1A[4 * c4 + 1] = fmaf(h0A, wv.y, h1A[4 * c4 + 1]);
                h1B[4 * c4 + 1] = fmaf(h0B, wv.y, h1B[4 * c4 + 1]);
                h1A[4 * c4 + 2] = fmaf(h0A, wv.z, h1A[4 * c4 + 2]);
                h1B[4 * c4 + 2] = fmaf(h0B, wv.z, h1B[4 * c4 + 2]);
                h1A[4 * c4 + 3] = fmaf(h0A, wv.w, h1A[4 * c4 + 3]);
                h1B[4 * c4 + 3] = fmaf(h0B, wv.w, h1B[4 * c4 + 3]);
            }
        }
        // bias + gelu
        {
            const float4* b1r = (const float4*)(smem + OFF_B1);
#pragma unroll
            for (int c4 = 0; c4 < 16; ++c4) {
                float4 bv = b1r[c4];
                h1A[4 * c4 + 0] = gelu_f(h1A[4 * c4 + 0] + bv.x);
                h1B[4 * c4 + 0] = gelu_f(h1B[4 * c4 + 0] + bv.x);
                h1A[4 * c4 + 1] = gelu_f(h1A[4 * c4 + 1] + bv.y);
                h1B[4 * c4 + 1] = gelu_f(h1B[4 * c4 + 1] + bv.y);
                h1A[4 * c4 + 2] = gelu_f(h1A[4 * c4 + 2] + bv.z);
                h1B[4 * c4 + 2] = gelu_f(h1B[4 * c4 + 2] + bv.z);
                h1A[4 * c4 + 3] = gelu_f(h1A[4 * c4 + 3] + bv.w);
                h1B[4 * c4 + 3] = gelu_f(h1B[4 * c4 + 3] + bv.w);
            }
        }

        // ---- layer2 (16 output chunks of 8), weights shared A/B ----
        float* saccA = sacc + (dA - q0) * 129;
        float* saccB = sacc + (dB - q0) * 129;
        const float4* rA = (const float4*)(rndata + (size_t)sA * 128);
        const float4* rB = (const float4*)(rndata + (size_t)sB * 128);
#pragma unroll 1
        for (int jj = 0; jj < 16; ++jj) {
            const float4* bb = (const float4*)(smem + OFF_B2 + jj * 8);
            float4 b20 = bb[0], b21 = bb[1];
            float4 rA0 = rA[jj * 2], rA1 = rA[jj * 2 + 1];
            float4 rB0 = rB[jj * 2], rB1 = rB[jj * 2 + 1];
            float accA[8] = {b20.x, b20.y, b20.z, b20.w, b21.x, b21.y, b21.z, b21.w};
            float accB[8] = {b20.x, b20.y, b20.z, b20.w, b21.x, b21.y, b21.z, b21.w};
            const float* w2c = smem + OFF_W2 + jj * 8;
#pragma unroll
            for (int i2 = 0; i2 < 64; ++i2) {
                const float4* wr = (const float4*)(w2c + i2 * 128);
                float4 w0v = wr[0], w1v = wr[1];
                accA[0] = fmaf(h1A[i2], w0v.x, accA[0]);
                accB[0] = fmaf(h1B[i2], w0v.x, accB[0]);
                accA[1] = fmaf(h1A[i2], w0v.y, accA[1]);
                accB[1] = fmaf(h1B[i2], w0v.y, accB[1]);
                accA[2] = fmaf(h1A[i2], w0v.z, accA[2]);
                accB[2] = fmaf(h1B[i2], w0v.z, accB[2]);
                accA[3] = fmaf(h1A[i2], w0v.w, accA[3]);
                accB[3] = fmaf(h1B[i2], w0v.w, accB[3]);
                accA[4] = fmaf(h1A[i2], w1v.x, accA[4]);
                accB[4] = fmaf(h1B[i2], w1v.x, accB[4]);
                accA[5] = fmaf(h1A[i2], w1v.y, accA[5]);
                accB[5] = fmaf(h1B[i2], w1v.y, accB[5]);
                accA[6] = fmaf(h1A[i2], w1v.z, accA[6]);
                accB[6] = fmaf(h1B[i2], w1v.z, accB[6]);
                accA[7] = fmaf(h1A[i2], w1v.w, accA[7]);
                accB[7] = fmaf(h1B[i2], w1v.w, accB[7]);
            }
            if (vA) {
                atomicAdd(&saccA[jj * 8 + 0], accA[0] * rA0.x);
                atomicAdd(&saccA[jj * 8 + 1], accA[1] * rA0.y);
                atomicAdd(&saccA[jj * 8 + 2], accA[2] * rA0.z);
                atomicAdd(&saccA[jj * 8 + 3], accA[3] * rA0.w);
                atomicAdd(&saccA[jj * 8 + 4], accA[4] * rA1.x);
                atomicAdd(&saccA[jj * 8 + 5], accA[5] * rA1.y);
                atomicAdd(&saccA[jj * 8 + 6], accA[6] * rA1.z);
                atomicAdd(&saccA[jj * 8 + 7], accA[7] * rA1.w);
            }
            if (vB) {
                atomicAdd(&saccB[jj * 8 + 0], accB[0] * rB0.x);
                atomicAdd(&saccB[jj * 8 + 1], accB[1] * rB0.y);
                atomicAdd(&saccB[jj * 8 + 2], accB[2] * rB0.z);
                atomicAdd(&saccB[jj * 8 + 3], accB[3] * rB0.w);
                atomicAdd(&saccB[jj * 8 + 4], accB[4] * rB1.x);
                atomicAdd(&saccB[jj * 8 + 5], accB[5] * rB1.y);
                atomicAdd(&saccB[jj * 8 + 6], accB[6] * rB1.z);
                atomicAdd(&saccB[jj * 8 + 7], accB[7] * rB1.w);
            }
        }
    }
    __syncthreads();

    if (!FUSED_PROJ) {
        // write per-query mean to global agg (coalesced across c)
        for (int idx = threadIdx.x; idx < QB * 128; idx += 256) {
            int ql = idx >> 7, c = idx & 127;
            int q  = q0 + ql;
            if (q < qend) {
                float deg = (float)(start[q + 1] - start[q]);
                agg[(size_t)q * 128 + c] = sacc[ql * 129 + c] / fmaxf(deg, 1.f);
            }
        }
    } else {
        if (threadIdx.x < QB) {
            int q = q0 + threadIdx.x;
            if (q < nq) {
                float deg = (float)(start[q + 1] - start[q]);
                float inv = 1.0f / fmaxf(deg, 1.f);
                const float* aq = &sacc[threadIdx.x * 129];
                float o0 = pb1[0], o1 = pb1[1], o2 = pb1[2], o3 = pb1[3];
#pragma unroll 1
                for (int jj = 0; jj < 256; jj += 8) {
                    float acc[8];
#pragma unroll
                    for (int u = 0; u < 8; ++u) acc[u] = pb0[jj + u];
#pragma unroll
                    for (int i = 0; i < 128; ++i) {
                        float av = aq[i] * inv;
#pragma unroll
                        for (int u = 0; u < 8; ++u)
                            acc[u] = fmaf(av, P0[i * 256 + jj + u], acc[u]);
                    }
#pragma unroll
                    for (int u = 0; u < 8; ++u) {
                        float h = gelu_f(acc[u]);
                        o0 = fmaf(h, P1[(jj + u) * 4 + 0], o0);
                        o1 = fmaf(h, P1[(jj + u) * 4 + 1], o1);
                        o2 = fmaf(h, P1[(jj + u) * 4 + 2], o2);
                        o3 = fmaf(h, P1[(jj + u) * 4 + 3], o3);
                    }
                }
                float4* o4 = (float4*)(out + (size_t)q * 4);
                *o4 = make_float4(o0, o1, o2, o3);
            }
        }
    }
}

// ---------- projection (path A) ----------

__global__ __launch_bounds__(256) void proj_kernel(
    const float* __restrict__ agg,      // [NQ,128] mean
    const float* __restrict__ P0, const float* __restrict__ pb0,
    const float* __restrict__ P1, const float* __restrict__ pb1,
    float* __restrict__ out, int nq)
{
    int q = blockIdx.x * blockDim.x + threadIdx.x;
    if (q >= nq) return;

    float a[128];
    const float4* ag4 = (const float4*)(agg + (size_t)q * 128);
#pragma unroll
    for (int i = 0; i < 32; ++i) {
        float4 v = ag4[i];
        a[4 * i + 0] = v.x; a[4 * i + 1] = v.y;
        a[4 * i + 2] = v.z; a[4 * i + 3] = v.w;
    }

    float o0 = pb1[0], o1 = pb1[1], o2 = pb1[2], o3 = pb1[3];
#pragma unroll 1
    for (int jj = 0; jj < 256; jj += 8) {
        float acc[8];
#pragma unroll
        for (int u = 0; u < 8; ++u) acc[u] = pb0[jj + u];
#pragma unroll
        for (int i = 0; i < 128; ++i) {
            float av = a[i];
#pragma unroll
            for (int u = 0; u < 8; ++u)
                acc[u] = fmaf(av, P0[i * 256 + jj + u], acc[u]);
        }
#pragma unroll
        for (int u = 0; u < 8; ++u) {
            float h = gelu_f(acc[u]);
            o0 = fmaf(h, P1[(jj + u) * 4 + 0], o0);
            o1 = fmaf(h, P1[(jj + u) * 4 + 1], o1);
            o2 = fmaf(h, P1[(jj + u) * 4 + 2], o2);
            o3 = fmaf(h, P1[(jj + u) * 4 + 3], o3);
        }
    }
    float4* o4 = (float4*)(out + (size_t)q * 4);
    *o4 = make_float4(o0, o1, o2, o3);
}

extern "C" void kernel_launch(void* const* d_in, const int* in_sizes, int n_in,
                              void* d_out, int out_size, void* d_ws, size_t ws_size,
                              hipStream_t stream)
{
    const float* rndata = (const float*)d_in[0];
    const float* qpos   = (const float*)d_in[1];
    const float* lpos   = (const float*)d_in[2];
    const int*   dst    = (const int*)d_in[3];
    const int*   src    = (const int*)d_in[4];
    const float* W0  = (const float*)d_in[5];
    const float* b0  = (const float*)d_in[6];
    const float* W1  = (const float*)d_in[7];
    const float* b1  = (const float*)d_in[8];
    const float* W2  = (const float*)d_in[9];
    const float* b2  = (const float*)d_in[10];
    const float* P0  = (const float*)d_in[11];
    const float* pb0 = (const float*)d_in[12];
    const float* P1  = (const float*)d_in[13];
    const float* pb1 = (const float*)d_in[14];

    int nq = in_sizes[1] / 3;
    int E  = in_sizes[3];

    // ws layout: [agg nq*128 (path A)] [hist] [cursor] [start] [dsts] [srcs]
    size_t agg_bytes  = (size_t)nq * 128 * sizeof(float);
    size_t sort_bytes = 0;
    {
        size_t o = 0;
        o += ((size_t)nq * sizeof(int) + 15) & ~(size_t)15;
        o += ((size_t)nq * sizeof(int) + 15) & ~(size_t)15;
        o += ((size_t)(nq + 1) * sizeof(int) + 15) & ~(size_t)15;
        o += ((size_t)E * sizeof(int) + 15) & ~(size_t)15;
        o += ((size_t)E * sizeof(int) + 15) & ~(size_t)15;
        sort_bytes = o;
    }
    bool path_a = (agg_bytes + sort_bytes) <= ws_size;

    size_t off = path_a ? agg_bytes : 0;
    auto alloc = [&](size_t bytes) {
        void* p = (char*)d_ws + off;
        off += (bytes + 15) & ~(size_t)15;
        return p;
    };
    float* agg   = (float*)d_ws;  // path A only
    int* hist    = (int*)alloc((size_t)nq * sizeof(int));
    int* cursor  = (int*)alloc((size_t)nq * sizeof(int));
    int* start   = (int*)alloc((size_t)(nq + 1) * sizeof(int));
    int* dsts    = (int*)alloc((size_t)E * sizeof(int));
    int* srcs    = (int*)alloc((size_t)E * sizeof(int));

    size_t histpad = ((size_t)nq * sizeof(int) + 15) & ~(size_t)15;
    hipMemsetAsync(hist, 0, 2 * histpad, stream);

    hist_kernel<<<(E + 255) / 256, 256, 0, stream>>>(dst, hist, E);
    scan_kernel<<<1, 1024, 0, stream>>>(hist, start, nq);
    scatter_kernel<<<(E + 255) / 256, 256, 0, stream>>>(dst, src, start, cursor, dsts, srcs, E);

    constexpr int    QB_BIG     = 48;
    constexpr int    QB_SMALL   = 23;
    constexpr size_t SMEM_BIG   = (size_t)(12992 + QB_BIG   * 129) * 4;  // 76,736 B
    constexpr size_t SMEM_SMALL = (size_t)(12992 + QB_SMALL * 129) * 4;  // 63,836 B

    if (path_a) {
        bool big = hipFuncSetAttribute(
            reinterpret_cast<const void*>(&fused_kernel<QB_BIG, false>),
            hipFuncAttributeMaxDynamicSharedMemorySize, (int)SMEM_BIG) == hipSuccess;
        if (big) {
            int nb = (nq + QB_BIG - 1) / QB_BIG;
            fused_kernel<QB_BIG, false><<<nb, 256, SMEM_BIG, stream>>>(
                rndata, qpos, lpos, dsts, srcs, start,
                W0, b0, W1, b1, W2, b2, P0, pb0, P1, pb1, agg, nullptr, nq);
        } else {
            int nb = (nq + QB_SMALL - 1) / QB_SMALL;
            fused_kernel<QB_SMALL, false><<<nb, 256, SMEM_SMALL, stream>>>(
                rndata, qpos, lpos, dsts, srcs, start,
                W0, b0, W1, b1, W2, b2, P0, pb0, P1, pb1, agg, nullptr, nq);
        }
        proj_kernel<<<(nq + 255) / 256, 256, 0, stream>>>(
            agg, P0, pb0, P1, pb1, (float*)d_out, nq);
    } else {
        bool big = hipFuncSetAttribute(
            reinterpret_cast<const void*>(&fused_kernel<QB_BIG, true>),
            hipFuncAttributeMaxDynamicSharedMemorySize, (int)SMEM_BIG) == hipSuccess;
        if (big) {
            int nb = (nq + QB_BIG - 1) / QB_BIG;
            fused_kernel<QB_BIG, true><<<nb, 256, SMEM_BIG, stream>>>(
                rndata, qpos, lpos, dsts, srcs, start,
                W0, b0, W1, b1, W2, b2, P0, pb0, P1, pb1, nullptr, (float*)d_out, nq);
        } else {
            int nb = (nq + QB_SMALL - 1) / QB_SMALL;
            fused_kernel<QB_SMALL, true><<<nb, 256, SMEM_SMALL, stream>>>(
                rndata, qpos, lpos, dsts, srcs, start,
                W0, b0, W1, b1, W2, b2, P0, pb0, P1, pb1, nullptr, (float*)d_out, nq);
        }
    }
}

// Round 7
// 2400.077 us; speedup vs baseline: 6.6787x; 5.8520x over previous
//
#include <hip/hip_runtime.h>

// GNODecoder round 7: the 2-edge-per-lane experiments (r5/r6) spill at the
// allocator's hard 128-VGPR choice -> abandoned. Round-4 body is the proven
// operating point (128 VGPR, no spill); its gap to the ~1 ms LDS floor is
// latency hiding (2 waves/SIMD). Fix via launch shape: ONE 1024-thread block
// (16 waves) per CU-slot sharing a single 52 KB weight copy + QB=196 sacc
// (152.8 KB LDS, opt-in). VGPR=128 => 4 waves/SIMD resident = 2x round-4
// hiding with identical per-CU LDS demand. Fallback QB=23 (63.6 KB).

#define BLOCK 1024
#define NW    16   // waves per block

// LDS float offsets (round-4 proven layout)
#define OFF_W0   0      // [6*64]
#define OFF_B0   384    // [64]
#define OFF_W1   448    // [64*64]
#define OFF_B1   4544   // [64]
#define OFF_W2   4608   // [64*128]
#define OFF_B2   12800  // [128]
#define OFF_SACC 12928  // [QB*129]

__device__ __forceinline__ float gelu_f(float x) {
    // jax.nn.gelu default (approximate=True, tanh form)
    float x3 = x * x * x;
    float t  = 0.7978845608028654f * fmaf(0.044715f, x3, x);
    float e  = __expf(2.0f * t);
    float r  = __builtin_amdgcn_rcpf(e + 1.0f);
    return 0.5f * x * (1.0f + (1.0f - 2.0f * r));
}

// ---------- sort machinery (proven) ----------

__global__ void hist_kernel(const int* __restrict__ dst, int* __restrict__ hist, int E) {
    int e = blockIdx.x * blockDim.x + threadIdx.x;
    if (e < E) atomicAdd(&hist[dst[e]], 1);
}

__global__ __launch_bounds__(1024) void scan_kernel(const int* __restrict__ hist,
                                                    int* __restrict__ start, int n) {
    __shared__ int wsum[16];
    __shared__ int woff[16];
    int tid = threadIdx.x;
    int lane = tid & 63, wid = tid >> 6;
    int carry = 0;  // meaningful on tid 0 only
    for (int base = 0; base < n; base += 1024) {
        int i = base + tid;
        int v = (i < n) ? hist[i] : 0;
        int incl = v;
#pragma unroll
        for (int off = 1; off < 64; off <<= 1) {
            int t = __shfl_up(incl, off, 64);
            if (lane >= off) incl += t;
        }
        if (lane == 63) wsum[wid] = incl;
        __syncthreads();
        if (tid == 0) {
            int acc = carry;
#pragma unroll
            for (int w = 0; w < 16; ++w) { woff[w] = acc; acc += wsum[w]; }
            carry = acc;
        }
        __syncthreads();
        if (i < n) start[i] = woff[wid] + incl - v;
        __syncthreads();
    }
    if (threadIdx.x == 0) start[n] = carry;
}

__global__ void scatter_kernel(const int* __restrict__ dst, const int* __restrict__ src,
                               const int* __restrict__ start, int* __restrict__ cursor,
                               int* __restrict__ dsts, int* __restrict__ srcs, int E) {
    int e = blockIdx.x * blockDim.x + threadIdx.x;
    if (e >= E) return;
    int d = dst[e];
    int pos = start[d] + atomicAdd(&cursor[d], 1);
    dsts[pos] = d;
    srcs[pos] = src[e];
}

// ---------- fused: round-4 per-edge body, 16-wave block, shared sacc ----------

template <int QB, bool FUSED_PROJ>
__global__ __launch_bounds__(BLOCK, 4) void fused_kernel(
    const float* __restrict__ rndata,   // [NL,128]
    const float* __restrict__ qpos,     // [NQ,3]
    const float* __restrict__ lpos,     // [NL,3]
    const int*   __restrict__ dsts,     // [E] sorted by dst
    const int*   __restrict__ srcs,     // [E]
    const int*   __restrict__ start,    // [NQ+1]
    const float* __restrict__ W0, const float* __restrict__ b0,
    const float* __restrict__ W1, const float* __restrict__ b1,
    const float* __restrict__ W2, const float* __restrict__ b2,
    const float* __restrict__ P0, const float* __restrict__ pb0,
    const float* __restrict__ P1, const float* __restrict__ pb1,
    float* __restrict__ agg,            // [NQ,128] mean (path A)
    float* __restrict__ out,            // [NQ,4]   (FUSED_PROJ)
    int nq)
{
    extern __shared__ float smem[];
    int tid = threadIdx.x;

    // ---- stage weights (one copy per 16-wave block) ----
    ((float4*)(smem + OFF_W1))[tid] = ((const float4*)W1)[tid];            // 1024 f4
    ((float4*)(smem + OFF_W2))[tid]        = ((const float4*)W2)[tid];     // 2048 f4
    ((float4*)(smem + OFF_W2))[tid + 1024] = ((const float4*)W2)[tid + 1024];
    if (tid < 96)       ((float4*)(smem + OFF_W0))[tid]       = ((const float4*)W0)[tid];
    else if (tid < 112) ((float4*)(smem + OFF_B0))[tid - 96]  = ((const float4*)b0)[tid - 96];
    else if (tid < 128) ((float4*)(smem + OFF_B1))[tid - 112] = ((const float4*)b1)[tid - 112];
    else if (tid < 160) ((float4*)(smem + OFF_B2))[tid - 128] = ((const float4*)b2)[tid - 128];
    for (int i = tid; i < QB * 129; i += BLOCK) smem[OFF_SACC + i] = 0.f;
    __syncthreads();

    const float* sw0 = smem + OFF_W0;
    const float* sb0 = smem + OFF_B0;
    const float* sw1 = smem + OFF_W1;
    const float* sb1 = smem + OFF_B1;
    const float* sw2 = smem + OFF_W2;
    const float* sb2 = smem + OFF_B2;
    float*       sacc = smem + OFF_SACC;   // stride 129

    int w = tid >> 6, lane = tid & 63;
    int q0   = blockIdx.x * QB;
    int qend = min(q0 + QB, nq);
    int e0 = start[q0], e1 = start[qend];

    for (int base = e0 + w * 64; base < e1; base += NW * 64) {
        int  e     = base + lane;
        bool valid = (e < e1);
        int  d = valid ? dsts[e] : q0;
        int  s = valid ? srcs[e] : 0;
        int  ql = d - q0;

        float q0c = qpos[d * 3 + 0], q1c = qpos[d * 3 + 1], q2c = qpos[d * 3 + 2];
        float l0c = lpos[s * 3 + 0], l1c = lpos[s * 3 + 1], l2c = lpos[s * 3 + 2];

        // layer 0: [6] -> [64], gelu
        float h0[64];
#pragma unroll
        for (int j = 0; j < 64; ++j) {
            float a = sb0[j];
            a = fmaf(q0c, sw0[0 * 64 + j], a);
            a = fmaf(q1c, sw0[1 * 64 + j], a);
            a = fmaf(q2c, sw0[2 * 64 + j], a);
            a = fmaf(l0c, sw0[3 * 64 + j], a);
            a = fmaf(l1c, sw0[4 * 64 + j], a);
            a = fmaf(l2c, sw0[5 * 64 + j], a);
            h0[j] = gelu_f(a);
        }

        // layer 1: [64] -> [64], gelu
        float h1[64];
#pragma unroll
        for (int jj = 0; jj < 64; jj += 8) {
            float acc[8];
#pragma unroll
            for (int u = 0; u < 8; ++u) acc[u] = sb1[jj + u];
#pragma unroll
            for (int i2 = 0; i2 < 64; ++i2) {
                float h = h0[i2];
#pragma unroll
                for (int u = 0; u < 8; ++u)
                    acc[u] = fmaf(h, sw1[i2 * 64 + jj + u], acc[u]);
            }
#pragma unroll
            for (int u = 0; u < 8; ++u) h1[jj + u] = gelu_f(acc[u]);
        }

        // layer 2: [64] -> [128], * rndata[src], LDS per-query accumulate
        const float4* r4   = (const float4*)(rndata + (size_t)s * 128);
        float*        aacc = &sacc[ql * 129];
#pragma unroll 1
        for (int jj = 0; jj < 128; jj += 8) {
            float acc[8];
#pragma unroll
            for (int u = 0; u < 8; ++u) acc[u] = sb2[jj + u];
#pragma unroll
            for (int i2 = 0; i2 < 64; ++i2) {
                float h = h1[i2];
#pragma unroll
                for (int u = 0; u < 8; ++u)
                    acc[u] = fmaf(h, sw2[i2 * 128 + jj + u], acc[u]);
            }
            float4 ra = r4[jj / 4], rb = r4[jj / 4 + 1];
            if (valid) {
                atomicAdd(&aacc[jj + 0], acc[0] * ra.x);
                atomicAdd(&aacc[jj + 1], acc[1] * ra.y);
                atomicAdd(&aacc[jj + 2], acc[2] * ra.z);
                atomicAdd(&aacc[jj + 3], acc[3] * ra.w);
                atomicAdd(&aacc[jj + 4], acc[4] * rb.x);
                atomicAdd(&aacc[jj + 5], acc[5] * rb.y);
                atomicAdd(&aacc[jj + 6], acc[6] * rb.z);
                atomicAdd(&aacc[jj + 7], acc[7] * rb.w);
            }
        }
    }
    __syncthreads();

    if (!FUSED_PROJ) {
        // write per-query mean to global agg (coalesced across c)
        for (int idx = tid; idx < QB * 128; idx += BLOCK) {
            int ql = idx >> 7, c = idx & 127;
            int q  = q0 + ql;
            if (q < qend) {
                float deg = (float)(start[q + 1] - start[q]);
                agg[(size_t)q * 128 + c] = sacc[ql * 129 + c] / fmaxf(deg, 1.f);
            }
        }
    } else {
        if (tid < QB) {
            int q = q0 + tid;
            if (q < nq) {
                float deg = (float)(start[q + 1] - start[q]);
                float inv = 1.0f / fmaxf(deg, 1.f);
                const float* aq = &sacc[tid * 129];
                float o0 = pb1[0], o1 = pb1[1], o2 = pb1[2], o3 = pb1[3];
#pragma unroll 1
                for (int jj = 0; jj < 256; jj += 8) {
                    float acc[8];
#pragma unroll
                    for (int u = 0; u < 8; ++u) acc[u] = pb0[jj + u];
#pragma unroll
                    for (int i = 0; i < 128; ++i) {
                        float av = aq[i] * inv;
#pragma unroll
                        for (int u = 0; u < 8; ++u)
                            acc[u] = fmaf(av, P0[i * 256 + jj + u], acc[u]);
                    }
#pragma unroll
                    for (int u = 0; u < 8; ++u) {
                        float h = gelu_f(acc[u]);
                        o0 = fmaf(h, P1[(jj + u) * 4 + 0], o0);
                        o1 = fmaf(h, P1[(jj + u) * 4 + 1], o1);
                        o2 = fmaf(h, P1[(jj + u) * 4 + 2], o2);
                        o3 = fmaf(h, P1[(jj + u) * 4 + 3], o3);
                    }
                }
                float4* o4 = (float4*)(out + (size_t)q * 4);
                *o4 = make_float4(o0, o1, o2, o3);
            }
        }
    }
}

// ---------- projection (path A) ----------

__global__ __launch_bounds__(256) void proj_kernel(
    const float* __restrict__ agg,      // [NQ,128] mean
    const float* __restrict__ P0, const float* __restrict__ pb0,
    const float* __restrict__ P1, const float* __restrict__ pb1,
    float* __restrict__ out, int nq)
{
    int q = blockIdx.x * blockDim.x + threadIdx.x;
    if (q >= nq) return;

    float a[128];
    const float4* ag4 = (const float4*)(agg + (size_t)q * 128);
#pragma unroll
    for (int i = 0; i < 32; ++i) {
        float4 v = ag4[i];
        a[4 * i + 0] = v.x; a[4 * i + 1] = v.y;
        a[4 * i + 2] = v.z; a[4 * i + 3] = v.w;
    }

    float o0 = pb1[0], o1 = pb1[1], o2 = pb1[2], o3 = pb1[3];
#pragma unroll 1
    for (int jj = 0; jj < 256; jj += 8) {
        float acc[8];
#pragma unroll
        for (int u = 0; u < 8; ++u) acc[u] = pb0[jj + u];
#pragma unroll
        for (int i = 0; i < 128; ++i) {
            float av = a[i];
#pragma unroll
            for (int u = 0; u < 8; ++u)
                acc[u] = fmaf(av, P0[i * 256 + jj + u], acc[u]);
        }
#pragma unroll
        for (int u = 0; u < 8; ++u) {
            float h = gelu_f(acc[u]);
            o0 = fmaf(h, P1[(jj + u) * 4 + 0], o0);
            o1 = fmaf(h, P1[(jj + u) * 4 + 1], o1);
            o2 = fmaf(h, P1[(jj + u) * 4 + 2], o2);
            o3 = fmaf(h, P1[(jj + u) * 4 + 3], o3);
        }
    }
    float4* o4 = (float4*)(out + (size_t)q * 4);
    *o4 = make_float4(o0, o1, o2, o3);
}

extern "C" void kernel_launch(void* const* d_in, const int* in_sizes, int n_in,
                              void* d_out, int out_size, void* d_ws, size_t ws_size,
                              hipStream_t stream)
{
    const float* rndata = (const float*)d_in[0];
    const float* qpos   = (const float*)d_in[1];
    const float* lpos   = (const float*)d_in[2];
    const int*   dst    = (const int*)d_in[3];
    const int*   src    = (const int*)d_in[4];
    const float* W0  = (const float*)d_in[5];
    const float* b0  = (const float*)d_in[6];
    const float* W1  = (const float*)d_in[7];
    const float* b1  = (const float*)d_in[8];
    const float* W2  = (const float*)d_in[9];
    const float* b2  = (const float*)d_in[10];
    const float* P0  = (const float*)d_in[11];
    const float* pb0 = (const float*)d_in[12];
    const float* P1  = (const float*)d_in[13];
    const float* pb1 = (const float*)d_in[14];

    int nq = in_sizes[1] / 3;
    int E  = in_sizes[3];

    // ws layout: [agg nq*128 (path A)] [hist] [cursor] [start] [dsts] [srcs]
    size_t agg_bytes  = (size_t)nq * 128 * sizeof(float);
    size_t sort_bytes = 0;
    {
        size_t o = 0;
        o += ((size_t)nq * sizeof(int) + 15) & ~(size_t)15;
        o += ((size_t)nq * sizeof(int) + 15) & ~(size_t)15;
        o += ((size_t)(nq + 1) * sizeof(int) + 15) & ~(size_t)15;
        o += ((size_t)E * sizeof(int) + 15) & ~(size_t)15;
        o += ((size_t)E * sizeof(int) + 15) & ~(size_t)15;
        sort_bytes = o;
    }
    bool path_a = (agg_bytes + sort_bytes) <= ws_size;

    size_t off = path_a ? agg_bytes : 0;
    auto alloc = [&](size_t bytes) {
        void* p = (char*)d_ws + off;
        off += (bytes + 15) & ~(size_t)15;
        return p;
    };
    float* agg   = (float*)d_ws;  // path A only
    int* hist    = (int*)alloc((size_t)nq * sizeof(int));
    int* cursor  = (int*)alloc((size_t)nq * sizeof(int));
    int* start   = (int*)alloc((size_t)(nq + 1) * sizeof(int));
    int* dsts    = (int*)alloc((size_t)E * sizeof(int));
    int* srcs    = (int*)alloc((size_t)E * sizeof(int));

    size_t histpad = ((size_t)nq * sizeof(int) + 15) & ~(size_t)15;
    hipMemsetAsync(hist, 0, 2 * histpad, stream);

    hist_kernel<<<(E + 255) / 256, 256, 0, stream>>>(dst, hist, E);
    scan_kernel<<<1, 1024, 0, stream>>>(hist, start, nq);
    scatter_kernel<<<(E + 255) / 256, 256, 0, stream>>>(dst, src, start, cursor, dsts, srcs, E);

    constexpr int    QB_BIG     = 196;
    constexpr int    QB_SMALL   = 23;
    constexpr size_t SMEM_BIG   = (size_t)(12928 + QB_BIG   * 129) * 4;  // 152,848 B
    constexpr size_t SMEM_SMALL = (size_t)(12928 + QB_SMALL * 129) * 4;  // 63,580 B

    if (path_a) {
        bool big = hipFuncSetAttribute(
            reinterpret_cast<const void*>(&fused_kernel<QB_BIG, false>),
            hipFuncAttributeMaxDynamicSharedMemorySize, (int)SMEM_BIG) == hipSuccess;
        if (big) {
            int nb = (nq + QB_BIG - 1) / QB_BIG;
            fused_kernel<QB_BIG, false><<<nb, BLOCK, SMEM_BIG, stream>>>(
                rndata, qpos, lpos, dsts, srcs, start,
                W0, b0, W1, b1, W2, b2, P0, pb0, P1, pb1, agg, nullptr, nq);
        } else {
            int nb = (nq + QB_SMALL - 1) / QB_SMALL;
            fused_kernel<QB_SMALL, false><<<nb, BLOCK, SMEM_SMALL, stream>>>(
                rndata, qpos, lpos, dsts, srcs, start,
                W0, b0, W1, b1, W2, b2, P0, pb0, P1, pb1, agg, nullptr, nq);
        }
        proj_kernel<<<(nq + 255) / 256, 256, 0, stream>>>(
            agg, P0, pb0, P1, pb1, (float*)d_out, nq);
    } else {
        bool big = hipFuncSetAttribute(
            reinterpret_cast<const void*>(&fused_kernel<QB_BIG, true>),
            hipFuncAttributeMaxDynamicSharedMemorySize, (int)SMEM_BIG) == hipSuccess;
        if (big) {
            int nb = (nq + QB_BIG - 1) / QB_BIG;
            fused_kernel<QB_BIG, true><<<nb, BLOCK, SMEM_BIG, stream>>>(
                rndata, qpos, lpos, dsts, srcs, start,
                W0, b0, W1, b1, W2, b2, P0, pb0, P1, pb1, nullptr, (float*)d_out, nq);
        } else {
            int nb = (nq + QB_SMALL - 1) / QB_SMALL;
            fused_kernel<QB_SMALL, true><<<nb, BLOCK, SMEM_SMALL, stream>>>(
                rndata, qpos, lpos, dsts, srcs, start,
                W0, b0, W1, b1, W2, b2, P0, pb0, P1, pb1, nullptr, (float*)d_out, nq);
        }
    }
}